// Round 1
// 108.087 us; speedup vs baseline: 1.0198x; 1.0198x over previous
//
#include <hip/hip_runtime.h>
#include <hip/hip_bf16.h>
#include <math.h>

#define EPSV 1e-5f
#define HD   128
#define WROW 40   // Wt bf16 row stride: 80B = 5 quartets, gcd(5,8)=1 -> balanced

typedef __attribute__((ext_vector_type(8))) short bf16x8;   // 8 bf16 = 4 VGPRs
typedef __attribute__((ext_vector_type(4))) float f32x4;

static __device__ __forceinline__ unsigned int bfbits(float x) {
    __hip_bfloat16 h = __float2bfloat16(x);
    unsigned short u;
    __builtin_memcpy(&u, &h, 2);
    return (unsigned int)u;
}

// R14: two (b,t) tiles per block. The L2-streaming of W1/W2 (128KB/block,
// 268MB aggregate ~ 8us at L2 ceiling) was the largest per-block cost that
// replicates per tile; sharing each W load between two accumulators halves
// it, and Wt staging (W0 re-read + cvt + LDS write) amortizes 2x. Barrier
// count per block unchanged: both tiles' features+MFMA sit between B2/B3
// (no LDS cross-talk between tiles except disjoint hvec[t]). Grid halves to
// 1024 blocks (4 blocks/CU, 16 waves/CU).
// Numerics identical to R13: A-side hi-only bf16 (noise pools out over 256
// particles), W-side hi+lo compensation folded into one MFMA, constant
// features exact fp32 via cvec.
__global__ __launch_bounds__(256, 4) void net_fused(
    const float* __restrict__ x0g, const float* __restrict__ xg,
    const int*   __restrict__ Ng,  const float* __restrict__ basisg,
    const float* __restrict__ vg,  const float* __restrict__ Pg,
    const float* __restrict__ W0,  const float* __restrict__ b0,
    const float* __restrict__ W1,  const float* __restrict__ b1,
    const float* __restrict__ W2,  const float* __restrict__ b2,
    float* __restrict__ out, int Tn, int NDn, int nbt)
{
    __shared__ __align__(16) __hip_bfloat16 Wt[128 * WROW];  // [whi|wlo] rows
    __shared__ float cvec[2][HD];     // exact constant-feature contribution
    __shared__ float hvec[2][HD];     // pooled (atomic-accumulated) + logN
    __shared__ float h1vec[2][HD];    // layer-1 activations
    __shared__ float vred[2][4][3];   // v-mean wave partials

    const int bt0 = blockIdx.x * 2;
    int bt1g = bt0 + 1; if (bt1g >= nbt) bt1g = bt0;   // tail guard (benign dup)
    const int bts[2] = { bt0, bt1g };

    const int tid  = threadIdx.x;
    const int lane = tid & 63;
    const int wave = tid >> 6;
    const int quad = lane >> 4;
    const int lm   = lane & 15;

    // ---- per-particle global loads for both tiles (particle i = tid) ----
    float xi[2][3], vi[2][3];
    #pragma unroll
    for (int t = 0; t < 2; ++t) {
        const long pbase = ((long)bts[t] * NDn + tid) * 3;
        xi[t][0] = xg[pbase+0]; xi[t][1] = xg[pbase+1]; xi[t][2] = xg[pbase+2];
        vi[t][0] = vg[pbase+0]; vi[t][1] = vg[pbase+1]; vi[t][2] = vg[pbase+2];
    }

    // ---- v0 mean: wave shuffle reduce -> vred, per tile ----
    #pragma unroll
    for (int t = 0; t < 2; ++t) {
        float s0 = vi[t][0], s1 = vi[t][1], s2 = vi[t][2];
        #pragma unroll
        for (int off = 32; off > 0; off >>= 1) {
            s0 += __shfl_down(s0, off);
            s1 += __shfl_down(s1, off);
            s2 += __shfl_down(s2, off);
        }
        if (lane == 0) { vred[t][wave][0] = s0; vred[t][wave][1] = s1; vred[t][wave][2] = s2; }
    }

    // ---- Wt staging by threads 0..127 (once per block, serves both tiles) ----
    if (tid < 128) {
        const int RV[9] = {0, 1, 2, 3, 14, 15, 16, 17, 18};
        __hip_bfloat16 r1[32];
        #pragma unroll
        for (int kk = 0; kk < 32; ++kk) r1[kk] = __float2bfloat16(0.0f);
        if (tid < 127) {
            #pragma unroll
            for (int kk = 0; kk < 9; ++kk) {
                const float wv = W0[RV[kk] * 127 + tid];   // coalesced across tid
                const __hip_bfloat16 hi = __float2bfloat16(wv);
                r1[kk]      = hi;                                          // whi
                r1[16 + kk] = __float2bfloat16(wv - __bfloat162float(hi)); // wlo
            }
        }
        bf16x8* d1 = reinterpret_cast<bf16x8*>(&Wt[tid * WROW]);
        const bf16x8* s1v = reinterpret_cast<const bf16x8*>(r1);
        d1[0] = s1v[0]; d1[1] = s1v[1]; d1[2] = s1v[2]; d1[3] = s1v[3];
    }
    __syncthreads();                                             // B1

    const float inv_nd = 1.0f / (float)NDn;

    // ---- per-tile scalars, cvec, hvec init, packed features ----
    unsigned int Hf[2][5];
    #pragma unroll
    for (int t = 0; t < 2; ++t) {
        const int bt = bts[t];
        const int b  = bt / Tn;

        const float v00 = (vred[t][0][0]+vred[t][1][0]+vred[t][2][0]+vred[t][3][0]) * inv_nd;
        const float v01 = (vred[t][0][1]+vred[t][1][1]+vred[t][2][1]+vred[t][3][1]) * inv_nd;
        const float v02 = (vred[t][0][2]+vred[t][1][2]+vred[t][2][2]+vred[t][3][2]) * inv_nd;

        const float p0 = x0g[bt*3+0], p1 = x0g[bt*3+1], p2 = x0g[bt*3+2];
        float bas[3][3];
        #pragma unroll
        for (int k = 0; k < 3; ++k)
            #pragma unroll
            for (int c = 0; c < 3; ++c)
                bas[k][c] = basisg[(b*3 + k)*3 + c];

        const float x0n  = sqrtf(p0*p0 + p1*p1 + p2*p2) + EPSV;
        const float ix0n = 1.0f / x0n;
        const float x0u0 = p0*ix0n, x0u1 = p1*ix0n, x0u2 = p2*ix0n;

        const float v0n  = sqrtf(v00*v00 + v01*v01 + v02*v02) + EPSV;
        const float iv0n = 1.0f / v0n;
        const float v0u0 = v00*iv0n, v0u1 = v01*iv0n, v0u2 = v02*iv0n;

        const float logN = log1pf((float)Ng[bt]);

        // exact fp32 constant-feature contribution + hvec init
        if (tid < 128) {
            float c = 0.0f;
            if (tid < 127) {
                float fc[10];
                fc[0] = logN;
                fc[1] = x0n;
                fc[2] = x0u0*bas[0][0] + x0u1*bas[0][1] + x0u2*bas[0][2];
                fc[3] = x0u0*bas[1][0] + x0u1*bas[1][1] + x0u2*bas[1][2];
                fc[4] = x0u0*bas[2][0] + x0u1*bas[2][1] + x0u2*bas[2][2];
                fc[5] = v0n;
                fc[6] = v0u0*bas[0][0] + v0u1*bas[0][1] + v0u2*bas[0][2];
                fc[7] = v0u0*bas[1][0] + v0u1*bas[1][1] + v0u2*bas[1][2];
                fc[8] = v0u0*bas[2][0] + v0u1*bas[2][1] + v0u2*bas[2][2];
                fc[9] = x0u0*v0u0 + x0u1*v0u1 + x0u2*v0u2;
                c = b0[tid];
                #pragma unroll
                for (int i = 0; i < 10; ++i)
                    c = fmaf(fc[i], W0[(4 + i) * 127 + tid], c);
            }
            cvec[t][tid] = c;
            hvec[t][tid] = (tid == 127) ? logN : 0.0f;   // atomic-accumulation base
        }

        // varying features -> packed bf16-hi registers Hf[t][5]
        {
            const float xn  = sqrtf(xi[t][0]*xi[t][0] + xi[t][1]*xi[t][1] + xi[t][2]*xi[t][2]) + EPSV;
            const float ixn = 1.0f / xn;
            const float xu0 = xi[t][0]*ixn, xu1 = xi[t][1]*ixn, xu2 = xi[t][2]*ixn;

            const float c0 = vi[t][0] - v00, c1 = vi[t][1] - v01, c2 = vi[t][2] - v02;
            const float vn  = sqrtf(c0*c0 + c1*c1 + c2*c2) + EPSV;
            const float ivn = 1.0f / vn;
            const float vu0 = c0*ivn, vu1 = c1*ivn, vu2 = c2*ivn;

            float f[9];
            f[0] = xn;                                            // W0 row 0
            f[1] = xu0*bas[0][0] + xu1*bas[0][1] + xu2*bas[0][2]; // row 1
            f[2] = xu0*bas[1][0] + xu1*bas[1][1] + xu2*bas[1][2]; // row 2
            f[3] = xu0*bas[2][0] + xu1*bas[2][1] + xu2*bas[2][2]; // row 3
            f[4] = vn;                                            // row 14
            f[5] = vu0*bas[0][0] + vu1*bas[0][1] + vu2*bas[0][2]; // row 15
            f[6] = vu0*bas[1][0] + vu1*bas[1][1] + vu2*bas[1][2]; // row 16
            f[7] = vu0*bas[2][0] + vu1*bas[2][1] + vu2*bas[2][2]; // row 17
            f[8] = xu0*vu0 + xu1*vu1 + xu2*vu2;                   // row 18

            unsigned int hb[9];
            #pragma unroll
            for (int kk = 0; kk < 9; ++kk) hb[kk] = bfbits(f[kk]);
            #pragma unroll
            for (int j = 0; j < 4; ++j) Hf[t][j] = hb[2*j] | (hb[2*j+1] << 16);
            Hf[t][4] = hb[8];
        }
    }
    __syncthreads();                                             // B2

    // ---- layer 0 MFMA per tile: wave w owns particles [w*64,w*64+64) x 128 ----
    #pragma unroll
    for (int t = 0; t < 2; ++t) {
        float pooled[8];
        #pragma unroll
        for (int nt = 0; nt < 8; ++nt) pooled[nt] = 0.0f;

        #pragma unroll
        for (int mt = 0; mt < 4; ++mt) {
            // wave transpose: pull packed hi-features from src lane mt*16+lm
            const int src = mt*16 + lm;
            const unsigned int t0 = (unsigned int)__shfl((int)Hf[t][0], src);
            const unsigned int t1 = (unsigned int)__shfl((int)Hf[t][1], src);
            const unsigned int t2 = (unsigned int)__shfl((int)Hf[t][2], src);
            const unsigned int t3 = (unsigned int)__shfl((int)Hf[t][3], src);
            const unsigned int t4 = (unsigned int)__shfl((int)Hf[t][4], src);

            // A-frag: even quads (k0..7 / k16..23) = f0..7; odd quads = [f8,0,0,0]
            union { unsigned int u[4]; bf16x8 v; } a;
            const bool evenq = ((quad & 1) == 0);
            a.u[0] = evenq ? t0 : t4;
            a.u[1] = evenq ? t1 : 0u;
            a.u[2] = evenq ? t2 : 0u;
            a.u[3] = evenq ? t3 : 0u;
            const bf16x8 af = a.v;

            #pragma unroll
            for (int nt = 0; nt < 8; ++nt) {
                const bf16x8 bf = *reinterpret_cast<const bf16x8*>(
                    &Wt[(nt*16 + lm) * WROW + quad*8]);
                const float cl = cvec[t][nt*16 + lm];
                const f32x4 cin = {cl, cl, cl, cl};
                const f32x4 acc = __builtin_amdgcn_mfma_f32_16x16x32_bf16(af, bf, cin, 0, 0, 0);
                #pragma unroll
                for (int r = 0; r < 4; ++r)
                    pooled[nt] += fmaxf(acc[r], 0.01f*acc[r]);   // leaky_relu
            }
        }
        #pragma unroll
        for (int nt = 0; nt < 8; ++nt) {
            pooled[nt] += __shfl_xor(pooled[nt], 16);
            pooled[nt] += __shfl_xor(pooled[nt], 32);
        }
        if (lane < 16) {
            #pragma unroll
            for (int nt = 0; nt < 8; ++nt) {
                // column 127: zero weights + zero cvec -> pools exactly 0
                atomicAdd(&hvec[t][nt*16 + lane], pooled[nt] * inv_nd);  // ds_add_f32
            }
        }
    }
    __syncthreads();                                             // B3

    // ---- layer 1: thread j full-K GEMV, each W1 load serves both tiles ----
    if (tid < HD) {
        float a0 = b1[tid], a1 = a0;
        #pragma unroll 8
        for (int k = 0; k < HD; ++k) {
            const float w = W1[k*HD + tid];
            a0 = fmaf(hvec[0][k], w, a0);
            a1 = fmaf(hvec[1][k], w, a1);
        }
        h1vec[0][tid] = fmaxf(a0, 0.01f*a0);
        h1vec[1][tid] = fmaxf(a1, 0.01f*a1);
    }
    __syncthreads();                                             // B4

    // ---- layer 2 + output scale, each W2 load serves both tiles ----
    if (tid < HD) {
        float a0 = b2[tid], a1 = a0;
        #pragma unroll 8
        for (int k = 0; k < HD; ++k) {
            const float w = W2[k*HD + tid];
            a0 = fmaf(h1vec[0][k], w, a0);
            a1 = fmaf(h1vec[1][k], w, a1);
        }
        out[(long)bts[0] * HD + tid] = a0 / Pg[bts[0] / Tn];
        out[(long)bts[1] * HD + tid] = a1 / Pg[bts[1] / Tn];
    }
}

extern "C" void kernel_launch(void* const* d_in, const int* in_sizes, int n_in,
                              void* d_out, int out_size, void* d_ws, size_t ws_size,
                              hipStream_t stream) {
    const float* x0    = (const float*)d_in[0];
    const float* x     = (const float*)d_in[1];
    const int*   N     = (const int*)  d_in[2];
    const float* basis = (const float*)d_in[3];
    const float* v     = (const float*)d_in[4];
    const float* P200c = (const float*)d_in[5];
    const float* W0    = (const float*)d_in[6];
    const float* b0    = (const float*)d_in[7];
    const float* W1    = (const float*)d_in[8];
    const float* b1    = (const float*)d_in[9];
    const float* W2    = (const float*)d_in[10];
    const float* b2    = (const float*)d_in[11];
    float* out = (float*)d_out;

    const int B  = in_sizes[5];                 // P200c is [B]
    const int T  = in_sizes[2] / B;             // N is [B,T]
    const int ND = in_sizes[1] / (in_sizes[2] * 3);  // x is [B,T,ND,3]
    const int nbt = B * T;

    hipLaunchKernelGGL(net_fused, dim3((nbt + 1) / 2), dim3(256), 0, stream,
                       x0, x, N, basis, v, P200c, W0, b0, W1, b1, W2, b2,
                       out, T, ND, nbt);
}